// Round 3
// baseline (4018.426 us; speedup 1.0000x reference)
//
#include <hip/hip_runtime.h>
#include <hip/hip_bf16.h>
#include <math.h>

#define H 768
#define B 256
#define T 100
#define G4 3072   // 4*H

typedef __attribute__((ext_vector_type(8))) short short8;
typedef __attribute__((ext_vector_type(4))) float f32x4;

static __device__ __forceinline__ float sigm(float x) {
    return 1.0f / (1.0f + __expf(-x));
}
static __device__ __forceinline__ float tanh_fast(float x) {
    return 1.0f - 2.0f / (__expf(2.0f * x) + 1.0f);
}

// ---------------- prep kernels (once per launch) ----------------

__global__ void prep_weights(const float* __restrict__ Wih, const float* __restrict__ Whh,
                             const float* __restrict__ bih, const float* __restrict__ bhh,
                             __hip_bfloat16* __restrict__ Wc,    // 3072 x 768 (Wih+Whh)
                             __hip_bfloat16* __restrict__ Wcat,  // 3072 x 1536 [Wih|Whh]
                             float* __restrict__ bias)           // 3072
{
    int r = blockIdx.y;
    int k = blockIdx.x * 256 + threadIdx.x;
    float a = Wih[r * H + k];
    float b = Whh[r * H + k];
    Wc[r * H + k] = __float2bfloat16(a + b);
    Wcat[r * 1536 + k] = __float2bfloat16(a);
    Wcat[r * 1536 + H + k] = __float2bfloat16(b);
    if (blockIdx.x == 0 && threadIdx.x == 0) bias[r] = bih[r] + bhh[r];
}

__global__ void prep_post(const float* __restrict__ Wpost, __hip_bfloat16* __restrict__ Wp)
{
    int r = blockIdx.y;
    int k = blockIdx.x * 256 + threadIdx.x;
    Wp[r * H + k] = (r < 72) ? __float2bfloat16(Wpost[r * H + k]) : __float2bfloat16(0.0f);
}

__global__ void prep_state(const float* __restrict__ src, const float* __restrict__ h0,
                           const float* __restrict__ c0,
                           __hip_bfloat16* __restrict__ A0,  // 256 x 1536 [x0|h0]
                           float* __restrict__ c_ws)         // 256 x 768
{
    int b = blockIdx.y;
    int k = blockIdx.x * 256 + threadIdx.x;
    A0[b * 1536 + k] = __float2bfloat16(src[(b * 16 + 15) * H + k]);   // src[:, -1, :]
    A0[b * 1536 + H + k] = __float2bfloat16(h0[b * H + k]);
    c_ws[b * H + k] = c0[b * H + k];
}

__global__ void init_barrier(unsigned* __restrict__ cnt)
{
    if (threadIdx.x < 16) cnt[threadIdx.x] = 0u;
}

// ---------------- step 0 only: fused gates GEMM + cell (K = 1536) ----------------
__global__ __launch_bounds__(64) void lstm_step(
    const __hip_bfloat16* __restrict__ A,   // B x K  ([x0|h0])
    const __hip_bfloat16* __restrict__ W,   // 3072 x K (Wcat)
    const float* __restrict__ bias,
    float* __restrict__ c,                  // B x H fp32 (in place)
    __hip_bfloat16* __restrict__ h_out,     // B x H bf16 (= outs[0])
    int K)
{
    const int jt = blockIdx.x;
    const int mt = blockIdx.y;
    const int lane = threadIdx.x;
    const int col = lane & 15;
    const int quad = lane >> 4;

    const short* Ap  = (const short*)A + (size_t)(mt * 16 + col) * K + quad * 8;
    const short* Wb  = (const short*)W;
    const short* Wp0 = Wb + (size_t)(0 * H + jt * 16 + col) * K + quad * 8;
    const short* Wp1 = Wb + (size_t)(1 * H + jt * 16 + col) * K + quad * 8;
    const short* Wp2 = Wb + (size_t)(2 * H + jt * 16 + col) * K + quad * 8;
    const short* Wp3 = Wb + (size_t)(3 * H + jt * 16 + col) * K + quad * 8;

    f32x4 acc0 = {0.f,0.f,0.f,0.f}, acc1 = {0.f,0.f,0.f,0.f};
    f32x4 acc2 = {0.f,0.f,0.f,0.f}, acc3 = {0.f,0.f,0.f,0.f};

    for (int k = 0; k < K; k += 32) {
        short8 a  = *(const short8*)(Ap + k);
        short8 b0 = *(const short8*)(Wp0 + k);
        short8 b1 = *(const short8*)(Wp1 + k);
        short8 b2 = *(const short8*)(Wp2 + k);
        short8 b3 = *(const short8*)(Wp3 + k);
        acc0 = __builtin_amdgcn_mfma_f32_16x16x32_bf16(a, b0, acc0, 0, 0, 0);
        acc1 = __builtin_amdgcn_mfma_f32_16x16x32_bf16(a, b1, acc1, 0, 0, 0);
        acc2 = __builtin_amdgcn_mfma_f32_16x16x32_bf16(a, b2, acc2, 0, 0, 0);
        acc3 = __builtin_amdgcn_mfma_f32_16x16x32_bf16(a, b3, acc3, 0, 0, 0);
    }

    const int j = jt * 16 + col;
    const float bi = bias[0 * H + j];
    const float bf = bias[1 * H + j];
    const float bg = bias[2 * H + j];
    const float bo = bias[3 * H + j];

#pragma unroll
    for (int r = 0; r < 4; ++r) {
        const int bidx = mt * 16 + quad * 4 + r;
        float ig = acc0[r] + bi;
        float fg = acc1[r] + bf;
        float gg = acc2[r] + bg;
        float og = acc3[r] + bo;
        float cold = c[bidx * H + j];
        float cn = sigm(fg) * cold + sigm(ig) * tanh_fast(gg);
        float hn = sigm(og) * tanh_fast(cn);
        c[bidx * H + j] = cn;
        h_out[bidx * H + j] = __float2bfloat16(hn);
    }
}

// ---------------- persistent recurrence: steps 1..99 ----------------
// grid 256 blocks (16 mtg x 16 jtgrp) x 192 threads (3 waves, jt = jtgrp*3+wave).
// W slice resident in VGPRs (384/lane), c resident in 4 VGPRs/lane.
// Cross-step sync: per-mtg generation barrier over 16 blocks (device-scope).
#define LDS_STRIDE 776   // 768 + 8 shorts pad

__global__ __launch_bounds__(192, 1) void lstm_persist(
    const __hip_bfloat16* __restrict__ Wc,   // 3072 x 768 bf16
    const float* __restrict__ bias,          // 3072
    const float* __restrict__ c_ws,          // B x H fp32 (after step 0)
    __hip_bfloat16* outs,                    // T x B x H bf16 (outs[0] ready)
    unsigned* cnt)                           // 16 group counters (zeroed)
{
    const int mtg   = blockIdx.x >> 4;   // batch group 0..15
    const int jtgrp = blockIdx.x & 15;   // j group 0..15
    const int tid   = threadIdx.x;
    const int wave  = tid >> 6;
    const int lane  = tid & 63;
    const int col   = lane & 15;
    const int quad  = lane >> 4;
    const int jt    = jtgrp * 3 + wave;  // 0..47
    const int j     = jt * 16 + col;

    __shared__ short lds[16 * LDS_STRIDE];   // 24832 B

    // ---- load resident weights: 4 gates x 24 k-chunks x 8 bf16 = 384 VGPRs ----
    const short* Wb = (const short*)Wc;
    short8 w[4][24];
#pragma unroll
    for (int g = 0; g < 4; ++g)
#pragma unroll
        for (int kk = 0; kk < 24; ++kk)
            w[g][kk] = *(const short8*)(Wb + (size_t)(g * H + j) * H + kk * 32 + quad * 8);

    const float bi = bias[0 * H + j];
    const float bf = bias[1 * H + j];
    const float bg = bias[2 * H + j];
    const float bo = bias[3 * H + j];

    float c[4];
#pragma unroll
    for (int r = 0; r < 4; ++r)
        c[r] = c_ws[(size_t)(mtg * 16 + quad * 4 + r) * H + j];

    const short* outs_s = (const short*)outs;

    for (int t = 1; t < T; ++t) {
        // ---- wait until all 16 blocks of this batch group finished step t-1 ----
        const unsigned target = 16u * (unsigned)(t - 1);
        if (tid == 0) {
            int guard = 0;
            while (__hip_atomic_load(&cnt[mtg], __ATOMIC_RELAXED,
                                     __HIP_MEMORY_SCOPE_AGENT) < target) {
                __builtin_amdgcn_s_sleep(1);
                if (++guard > (1 << 25)) break;   // safety valve vs hang
            }
        }
        __syncthreads();        // also covers LDS WAR from previous iteration
        __threadfence();        // acquire: invalidate stale L1/L2 before h loads

        // ---- stage h(t-1)[16 batches][768] global -> LDS ----
        // 16 rows x 96 short8-chunks = 1536 chunks; 192 threads x 8 iters.
        const short* hsrc = outs_s + (size_t)(t - 1) * B * H + (size_t)mtg * 16 * H;
#pragma unroll
        for (int i = 0; i < 8; ++i) {
            int idx = tid + i * 192;          // 0..1535
            int b  = idx / 96;                // row 0..15
            int ch = idx % 96;                // chunk 0..95
            *(short8*)(&lds[b * LDS_STRIDE + ch * 8]) =
                *(const short8*)(hsrc + (size_t)b * H + ch * 8);
        }
        __syncthreads();

        // ---- gates GEMM from LDS x resident W ----
        f32x4 acc0 = {0.f,0.f,0.f,0.f}, acc1 = {0.f,0.f,0.f,0.f};
        f32x4 acc2 = {0.f,0.f,0.f,0.f}, acc3 = {0.f,0.f,0.f,0.f};
#pragma unroll
        for (int kk = 0; kk < 24; ++kk) {
            short8 a = *(const short8*)(&lds[col * LDS_STRIDE + kk * 32 + quad * 8]);
            acc0 = __builtin_amdgcn_mfma_f32_16x16x32_bf16(a, w[0][kk], acc0, 0, 0, 0);
            acc1 = __builtin_amdgcn_mfma_f32_16x16x32_bf16(a, w[1][kk], acc1, 0, 0, 0);
            acc2 = __builtin_amdgcn_mfma_f32_16x16x32_bf16(a, w[2][kk], acc2, 0, 0, 0);
            acc3 = __builtin_amdgcn_mfma_f32_16x16x32_bf16(a, w[3][kk], acc3, 0, 0, 0);
        }

        // ---- cell update (c in registers) + h store ----
        __hip_bfloat16* hdst = outs + (size_t)t * B * H;
#pragma unroll
        for (int r = 0; r < 4; ++r) {
            const int b = mtg * 16 + quad * 4 + r;
            float ig = acc0[r] + bi;
            float fg = acc1[r] + bf;
            float gg = acc2[r] + bg;
            float og = acc3[r] + bo;
            float cn = sigm(fg) * c[r] + sigm(ig) * tanh_fast(gg);
            c[r] = cn;
            hdst[(size_t)b * H + j] = __float2bfloat16(sigm(og) * tanh_fast(cn));
        }

        // ---- publish step t ----
        __threadfence();        // release: make h stores visible cross-XCD
        __syncthreads();        // order tid0's signal after all threads' stores
        if (tid == 0) atomicAdd(&cnt[mtg], 1u);
    }
}

// ---------------- post projection ----------------
__global__ __launch_bounds__(64) void proj(
    const __hip_bfloat16* __restrict__ Hs,   // T x B x H
    const __hip_bfloat16* __restrict__ Wp,   // 80 x H (padded bf16)
    const float* __restrict__ bpost,         // 72
    float* __restrict__ out)                 // B x T x 72
{
    const int mt = blockIdx.x;
    const int lane = threadIdx.x;
    const int col = lane & 15;
    const int quad = lane >> 4;

    const short* Ap = (const short*)Hs + (size_t)(mt * 16 + col) * H + quad * 8;
    const short* Wb = (const short*)Wp;

    f32x4 acc[5];
#pragma unroll
    for (int nt = 0; nt < 5; ++nt) acc[nt] = (f32x4){0.f, 0.f, 0.f, 0.f};

    for (int k = 0; k < H; k += 32) {
        short8 a = *(const short8*)(Ap + k);
#pragma unroll
        for (int nt = 0; nt < 5; ++nt) {
            short8 b = *(const short8*)(Wb + (size_t)(nt * 16 + col) * H + quad * 8 + k);
            acc[nt] = __builtin_amdgcn_mfma_f32_16x16x32_bf16(a, b, acc[nt], 0, 0, 0);
        }
    }

#pragma unroll
    for (int nt = 0; nt < 5; ++nt) {
        const int o = nt * 16 + col;
        if (o < 72) {
            const float bb = bpost[o];
#pragma unroll
            for (int r = 0; r < 4; ++r) {
                const int m = mt * 16 + quad * 4 + r;
                const int t = m >> 8;
                const int b = m & 255;
                out[((size_t)b * T + t) * 72 + o] = acc[nt][r] + bb;
            }
        }
    }
}

// ---------------- launch ----------------

extern "C" void kernel_launch(void* const* d_in, const int* in_sizes, int n_in,
                              void* d_out, int out_size, void* d_ws, size_t ws_size,
                              hipStream_t stream) {
    const float* src   = (const float*)d_in[0];
    const float* h0    = (const float*)d_in[2];
    const float* c0    = (const float*)d_in[3];
    const float* Wih   = (const float*)d_in[4];
    const float* Whh   = (const float*)d_in[5];
    const float* bih   = (const float*)d_in[6];
    const float* bhh   = (const float*)d_in[7];
    const float* Wpost = (const float*)d_in[8];
    const float* bpost = (const float*)d_in[9];
    float* out = (float*)d_out;

    char* ws = (char*)d_ws;
    __hip_bfloat16* Wcat = (__hip_bfloat16*)(ws + 0);          //  9,437,184 B
    __hip_bfloat16* Wc   = (__hip_bfloat16*)(ws + 9437184);    //  4,718,592 B
    float*          bias = (float*)(ws + 14155776);            //     12,288 B
    __hip_bfloat16* Wp   = (__hip_bfloat16*)(ws + 14168064);   //    122,880 B
    __hip_bfloat16* A0   = (__hip_bfloat16*)(ws + 14290944);   //    786,432 B
    float*          c_ws = (float*)(ws + 15077376);            //    786,432 B
    __hip_bfloat16* outs = (__hip_bfloat16*)(ws + 15863808);   // 39,321,600 B
    unsigned*       cnt  = (unsigned*)(ws + 55185408);         //         64 B

    prep_weights<<<dim3(3, G4), 256, 0, stream>>>(Wih, Whh, bih, bhh, Wc, Wcat, bias);
    prep_post<<<dim3(3, 80), 256, 0, stream>>>(Wpost, Wp);
    prep_state<<<dim3(3, B), 256, 0, stream>>>(src, h0, c0, A0, c_ws);
    init_barrier<<<1, 64, 0, stream>>>(cnt);

    // step 0: gates = [x0|h0] @ [Wih|Whh]^T + bias   (K = 1536)
    lstm_step<<<dim3(48, 16), 64, 0, stream>>>(A0, Wcat, bias, c_ws, outs, 1536);

    // steps 1..99 in one persistent kernel (weights VGPR-resident)
    lstm_persist<<<256, 192, 0, stream>>>(Wc, bias, c_ws, outs, cnt);

    proj<<<1600, 64, 0, stream>>>(outs, Wp, bpost, out);
}

// Round 4
// 1176.213 us; speedup vs baseline: 3.4164x; 3.4164x over previous
//
#include <hip/hip_runtime.h>
#include <hip/hip_bf16.h>
#include <math.h>

#define H 768
#define B 256
#define T 100
#define G4 3072   // 4*H

typedef __attribute__((ext_vector_type(8))) short short8;
typedef __attribute__((ext_vector_type(4))) float f32x4;
typedef unsigned long long u64;

static __device__ __forceinline__ float sigm(float x) {
    return 1.0f / (1.0f + __expf(-x));
}
static __device__ __forceinline__ float tanh_fast(float x) {
    return 1.0f - 2.0f / (__expf(2.0f * x) + 1.0f);
}

// ---------------- prep kernels (once per launch) ----------------

__global__ void prep_weights(const float* __restrict__ Wih, const float* __restrict__ Whh,
                             const float* __restrict__ bih, const float* __restrict__ bhh,
                             __hip_bfloat16* __restrict__ Wc,    // 3072 x 768 (Wih+Whh)
                             __hip_bfloat16* __restrict__ Wcat,  // 3072 x 1536 [Wih|Whh]
                             float* __restrict__ bias)           // 3072
{
    int r = blockIdx.y;
    int k = blockIdx.x * 256 + threadIdx.x;
    float a = Wih[r * H + k];
    float b = Whh[r * H + k];
    Wc[r * H + k] = __float2bfloat16(a + b);
    Wcat[r * 1536 + k] = __float2bfloat16(a);
    Wcat[r * 1536 + H + k] = __float2bfloat16(b);
    if (blockIdx.x == 0 && threadIdx.x == 0) bias[r] = bih[r] + bhh[r];
}

__global__ void prep_post(const float* __restrict__ Wpost, __hip_bfloat16* __restrict__ Wp)
{
    int r = blockIdx.y;
    int k = blockIdx.x * 256 + threadIdx.x;
    Wp[r * H + k] = (r < 72) ? __float2bfloat16(Wpost[r * H + k]) : __float2bfloat16(0.0f);
}

__global__ void prep_state(const float* __restrict__ src, const float* __restrict__ h0,
                           const float* __restrict__ c0,
                           __hip_bfloat16* __restrict__ A0,  // 256 x 1536 [x0|h0]
                           float* __restrict__ c_ws)         // 256 x 768
{
    int b = blockIdx.y;
    int k = blockIdx.x * 256 + threadIdx.x;
    A0[b * 1536 + k] = __float2bfloat16(src[(b * 16 + 15) * H + k]);   // src[:, -1, :]
    A0[b * 1536 + H + k] = __float2bfloat16(h0[b * H + k]);
    c_ws[b * H + k] = c0[b * H + k];
}

__global__ void init_barrier(unsigned* __restrict__ cnt)
{
    if (threadIdx.x < 16) cnt[threadIdx.x] = 0u;
}

// ---------------- step 0 only: fused gates GEMM + cell (K = 1536) ----------------
__global__ __launch_bounds__(64) void lstm_step(
    const __hip_bfloat16* __restrict__ A,   // B x K  ([x0|h0])
    const __hip_bfloat16* __restrict__ W,   // 3072 x K (Wcat)
    const float* __restrict__ bias,
    float* __restrict__ c,                  // B x H fp32 (in place)
    __hip_bfloat16* __restrict__ h_out,     // B x H bf16 (= outs[0])
    int K)
{
    const int jt = blockIdx.x;
    const int mt = blockIdx.y;
    const int lane = threadIdx.x;
    const int col = lane & 15;
    const int quad = lane >> 4;

    const short* Ap  = (const short*)A + (size_t)(mt * 16 + col) * K + quad * 8;
    const short* Wb  = (const short*)W;
    const short* Wp0 = Wb + (size_t)(0 * H + jt * 16 + col) * K + quad * 8;
    const short* Wp1 = Wb + (size_t)(1 * H + jt * 16 + col) * K + quad * 8;
    const short* Wp2 = Wb + (size_t)(2 * H + jt * 16 + col) * K + quad * 8;
    const short* Wp3 = Wb + (size_t)(3 * H + jt * 16 + col) * K + quad * 8;

    f32x4 acc0 = {0.f,0.f,0.f,0.f}, acc1 = {0.f,0.f,0.f,0.f};
    f32x4 acc2 = {0.f,0.f,0.f,0.f}, acc3 = {0.f,0.f,0.f,0.f};

    for (int k = 0; k < K; k += 32) {
        short8 a  = *(const short8*)(Ap + k);
        short8 b0 = *(const short8*)(Wp0 + k);
        short8 b1 = *(const short8*)(Wp1 + k);
        short8 b2 = *(const short8*)(Wp2 + k);
        short8 b3 = *(const short8*)(Wp3 + k);
        acc0 = __builtin_amdgcn_mfma_f32_16x16x32_bf16(a, b0, acc0, 0, 0, 0);
        acc1 = __builtin_amdgcn_mfma_f32_16x16x32_bf16(a, b1, acc1, 0, 0, 0);
        acc2 = __builtin_amdgcn_mfma_f32_16x16x32_bf16(a, b2, acc2, 0, 0, 0);
        acc3 = __builtin_amdgcn_mfma_f32_16x16x32_bf16(a, b3, acc3, 0, 0, 0);
    }

    const int j = jt * 16 + col;
    const float bi = bias[0 * H + j];
    const float bf = bias[1 * H + j];
    const float bg = bias[2 * H + j];
    const float bo = bias[3 * H + j];

#pragma unroll
    for (int r = 0; r < 4; ++r) {
        const int bidx = mt * 16 + quad * 4 + r;
        float ig = acc0[r] + bi;
        float fg = acc1[r] + bf;
        float gg = acc2[r] + bg;
        float og = acc3[r] + bo;
        float cold = c[bidx * H + j];
        float cn = sigm(fg) * cold + sigm(ig) * tanh_fast(gg);
        float hn = sigm(og) * tanh_fast(cn);
        c[bidx * H + j] = cn;
        h_out[bidx * H + j] = __float2bfloat16(hn);
    }
}

// ---------------- persistent recurrence: steps 1..99 ----------------
// grid 256 blocks (16 mtg x 16 jg) x 768 threads (12 waves = 3 jt x 4 gates).
// One gate per wave -> w[24] = 96 VGPRs, guaranteed register-resident.
// h stored/loaded via AGENT-scope relaxed atomics (LLC-coherent) -> NO fences.
#define LDS_H_STRIDE 776   // 768 + 8 shorts pad
#define XCH_STRIDE   17    // 16 + 1 pad floats

__global__ __launch_bounds__(768, 3) void lstm_persist(
    const __hip_bfloat16* __restrict__ Wc,   // 3072 x 768 bf16
    const float* __restrict__ bias,          // 3072
    const float* __restrict__ c_ws,          // B x H fp32 (after step 0)
    __hip_bfloat16* outs,                    // T x B x H bf16 (outs[0] ready)
    unsigned* cnt)                           // 16 group counters (zeroed)
{
    const int mtg  = blockIdx.x >> 4;    // batch group 0..15 (16 batches)
    const int jg   = blockIdx.x & 15;    // j group 0..15 (48 j values)
    const int tid  = threadIdx.x;
    const int wave = tid >> 6;           // 0..11
    const int lane = tid & 63;
    const int col  = lane & 15;
    const int quad = lane >> 4;
    const int jt_l = wave >> 2;          // 0..2  local j-tile
    const int gate = wave & 3;           // 0..3  (i,f,g,o)
    const int j    = jg * 48 + jt_l * 16 + col;   // this wave's j column

    __shared__ short lds_h[16 * LDS_H_STRIDE];        // 24832 B staged h tile
    __shared__ float xch[12 * 16 * XCH_STRIDE];       // 13056 B gate exchange

    // ---- resident weight slice: 1 gate x 16 j x 768 k -> 24 x short8 = 96 VGPRs ----
    const short* Wb = (const short*)Wc;
    short8 w[24];
#pragma unroll
    for (int kk = 0; kk < 24; ++kk)
        w[kk] = *(const short8*)(Wb + (size_t)(gate * H + j) * H + kk * 32 + quad * 8);

    // ---- cell-role state (threads 0..383: two adjacent-j cells each) ----
    const int p    = tid;                 // pair id if < 384
    const int bb   = p / 24;              // local batch 0..15
    const int jp   = p % 24;
    const int jloc = jp * 2;              // local j 0..46 (even)
    const int cjt  = jloc >> 4;           // j-tile of the pair
    const int jcol = jloc & 15;
    const int bglob = mtg * 16 + bb;
    const int jglob = jg * 48 + jloc;
    float c0v = 0.f, c1v = 0.f;
    float bi0=0,bi1=0,bf0=0,bf1=0,bg0=0,bg1=0,bo0=0,bo1=0;
    if (p < 384) {
        c0v = c_ws[(size_t)bglob * H + jglob];
        c1v = c_ws[(size_t)bglob * H + jglob + 1];
        bi0 = bias[0*H + jglob]; bi1 = bias[0*H + jglob + 1];
        bf0 = bias[1*H + jglob]; bf1 = bias[1*H + jglob + 1];
        bg0 = bias[2*H + jglob]; bg1 = bias[2*H + jglob + 1];
        bo0 = bias[3*H + jglob]; bo1 = bias[3*H + jglob + 1];
    }

    const short* outs_s = (const short*)outs;

    for (int t = 1; t < T; ++t) {
        // ---- wait: all 16 blocks of this batch group finished step t-1 ----
        const unsigned target = 16u * (unsigned)(t - 1);
        if (tid == 0 && target) {
            int guard = 0;
            while (__hip_atomic_load(&cnt[mtg], __ATOMIC_RELAXED,
                                     __HIP_MEMORY_SCOPE_AGENT) < target) {
                __builtin_amdgcn_s_sleep(1);
                if (++guard > (1 << 24)) break;   // safety valve vs hang
            }
        }
        __syncthreads();   // (A) broadcast "go"; also WAR for lds_h vs prev reads

        // ---- stage h(t-1)[16 batches][768] -> LDS via LLC-coherent 8B loads ----
        const u64* hsrc8 = (const u64*)(outs_s + (size_t)(t - 1) * B * H
                                               + (size_t)mtg * 16 * H);
#pragma unroll
        for (int i = 0; i < 4; ++i) {
            int idx = tid + i * 768;          // 0..3071 (16 rows x 192 ulongs)
            int br  = idx / 192;
            int ch  = idx % 192;
            u64 v = __hip_atomic_load(&hsrc8[br * 192 + ch],
                                      __ATOMIC_RELAXED, __HIP_MEMORY_SCOPE_AGENT);
            *(u64*)&lds_h[br * LDS_H_STRIDE + ch * 4] = v;
        }
        __syncthreads();   // (B) lds_h ready; also WAR for xch vs prev cell reads

        // ---- this wave: 16 batches x 16 j, ONE gate, K=768 ----
        f32x4 acc = {0.f, 0.f, 0.f, 0.f};
#pragma unroll
        for (int kk = 0; kk < 24; ++kk) {
            short8 a = *(const short8*)(&lds_h[col * LDS_H_STRIDE + kk * 32 + quad * 8]);
            acc = __builtin_amdgcn_mfma_f32_16x16x32_bf16(a, w[kk], acc, 0, 0, 0);
        }

        // ---- exchange gate tiles through LDS ----
        float* xw = &xch[(size_t)wave * 16 * XCH_STRIDE];
#pragma unroll
        for (int r = 0; r < 4; ++r)
            xw[(quad * 4 + r) * XCH_STRIDE + col] = acc[r];
        __syncthreads();   // (C) xch ready

        // ---- cell update: threads 0..383, two adjacent j each ----
        if (p < 384) {
            const float* xg = &xch[(size_t)(cjt * 4) * 16 * XCH_STRIDE + bb * XCH_STRIDE + jcol];
            const int gs = 16 * XCH_STRIDE;
            float i0 = xg[0*gs] + bi0, i1 = xg[0*gs + 1] + bi1;
            float f0 = xg[1*gs] + bf0, f1 = xg[1*gs + 1] + bf1;
            float g0 = xg[2*gs] + bg0, g1 = xg[2*gs + 1] + bg1;
            float o0 = xg[3*gs] + bo0, o1 = xg[3*gs + 1] + bo1;
            float cn0 = sigm(f0) * c0v + sigm(i0) * tanh_fast(g0);
            float cn1 = sigm(f1) * c1v + sigm(i1) * tanh_fast(g1);
            c0v = cn0; c1v = cn1;
            __hip_bfloat16 h0b = __float2bfloat16(sigm(o0) * tanh_fast(cn0));
            __hip_bfloat16 h1b = __float2bfloat16(sigm(o1) * tanh_fast(cn1));
            unsigned u = (unsigned)(*(unsigned short*)&h0b)
                       | ((unsigned)(*(unsigned short*)&h1b) << 16);
            unsigned* dst = (unsigned*)(outs_s + (size_t)t * B * H
                                               + (size_t)bglob * H + jglob);
            __hip_atomic_store(dst, u, __ATOMIC_RELAXED, __HIP_MEMORY_SCOPE_AGENT);
        }

        // ---- publish step t ----
        asm volatile("s_waitcnt vmcnt(0)" ::: "memory");  // h stores at LLC
        __syncthreads();   // (D) all threads drained before signal
        if (tid == 0) atomicAdd(&cnt[mtg], 1u);
    }
}

// ---------------- post projection ----------------
__global__ __launch_bounds__(64) void proj(
    const __hip_bfloat16* __restrict__ Hs,   // T x B x H
    const __hip_bfloat16* __restrict__ Wp,   // 80 x H (padded bf16)
    const float* __restrict__ bpost,         // 72
    float* __restrict__ out)                 // B x T x 72
{
    const int mt = blockIdx.x;
    const int lane = threadIdx.x;
    const int col = lane & 15;
    const int quad = lane >> 4;

    const short* Ap = (const short*)Hs + (size_t)(mt * 16 + col) * H + quad * 8;
    const short* Wb = (const short*)Wp;

    f32x4 acc[5];
#pragma unroll
    for (int nt = 0; nt < 5; ++nt) acc[nt] = (f32x4){0.f, 0.f, 0.f, 0.f};

    for (int k = 0; k < H; k += 32) {
        short8 a = *(const short8*)(Ap + k);
#pragma unroll
        for (int nt = 0; nt < 5; ++nt) {
            short8 b = *(const short8*)(Wb + (size_t)(nt * 16 + col) * H + quad * 8 + k);
            acc[nt] = __builtin_amdgcn_mfma_f32_16x16x32_bf16(a, b, acc[nt], 0, 0, 0);
        }
    }

#pragma unroll
    for (int nt = 0; nt < 5; ++nt) {
        const int o = nt * 16 + col;
        if (o < 72) {
            const float bb = bpost[o];
#pragma unroll
            for (int r = 0; r < 4; ++r) {
                const int m = mt * 16 + quad * 4 + r;
                const int t = m >> 8;
                const int b = m & 255;
                out[((size_t)b * T + t) * 72 + o] = acc[nt][r] + bb;
            }
        }
    }
}

// ---------------- launch ----------------

extern "C" void kernel_launch(void* const* d_in, const int* in_sizes, int n_in,
                              void* d_out, int out_size, void* d_ws, size_t ws_size,
                              hipStream_t stream) {
    const float* src   = (const float*)d_in[0];
    const float* h0    = (const float*)d_in[2];
    const float* c0    = (const float*)d_in[3];
    const float* Wih   = (const float*)d_in[4];
    const float* Whh   = (const float*)d_in[5];
    const float* bih   = (const float*)d_in[6];
    const float* bhh   = (const float*)d_in[7];
    const float* Wpost = (const float*)d_in[8];
    const float* bpost = (const float*)d_in[9];
    float* out = (float*)d_out;

    char* ws = (char*)d_ws;
    __hip_bfloat16* Wcat = (__hip_bfloat16*)(ws + 0);          //  9,437,184 B
    __hip_bfloat16* Wc   = (__hip_bfloat16*)(ws + 9437184);    //  4,718,592 B
    float*          bias = (float*)(ws + 14155776);            //     12,288 B
    __hip_bfloat16* Wp   = (__hip_bfloat16*)(ws + 14168064);   //    122,880 B
    __hip_bfloat16* A0   = (__hip_bfloat16*)(ws + 14290944);   //    786,432 B
    float*          c_ws = (float*)(ws + 15077376);            //    786,432 B
    __hip_bfloat16* outs = (__hip_bfloat16*)(ws + 15863808);   // 39,321,600 B
    unsigned*       cnt  = (unsigned*)(ws + 55185408);         //         64 B

    prep_weights<<<dim3(3, G4), 256, 0, stream>>>(Wih, Whh, bih, bhh, Wc, Wcat, bias);
    prep_post<<<dim3(3, 80), 256, 0, stream>>>(Wpost, Wp);
    prep_state<<<dim3(3, B), 256, 0, stream>>>(src, h0, c0, A0, c_ws);
    init_barrier<<<1, 64, 0, stream>>>(cnt);

    // step 0: gates = [x0|h0] @ [Wih|Whh]^T + bias   (K = 1536)
    lstm_step<<<dim3(48, 16), 64, 0, stream>>>(A0, Wcat, bias, c_ws, outs, 1536);

    // steps 1..99 in one persistent kernel (no fences, LLC-coherent h traffic)
    lstm_persist<<<256, 768, 0, stream>>>(Wc, bias, c_ws, outs, cnt);

    proj<<<1600, 64, 0, stream>>>(outs, Wp, bpost, out);
}

// Round 5
// 567.179 us; speedup vs baseline: 7.0849x; 2.0738x over previous
//
#include <hip/hip_runtime.h>
#include <hip/hip_bf16.h>
#include <math.h>

#define H 768
#define B 256
#define T 100
#define G4 3072   // 4*H

typedef __attribute__((ext_vector_type(8))) short short8;
typedef __attribute__((ext_vector_type(4))) float f32x4;
typedef unsigned long long u64;

static __device__ __forceinline__ float sigm(float x) {
    return 1.0f / (1.0f + __expf(-x));
}
static __device__ __forceinline__ float tanh_fast(float x) {
    return 1.0f - 2.0f / (__expf(2.0f * x) + 1.0f);
}

// ---------------- prep kernels (once per launch) ----------------

__global__ void prep_weights(const float* __restrict__ Wih, const float* __restrict__ Whh,
                             const float* __restrict__ bih, const float* __restrict__ bhh,
                             __hip_bfloat16* __restrict__ Wc,    // 3072 x 768 (Wih+Whh)
                             __hip_bfloat16* __restrict__ Wcat,  // 3072 x 1536 [Wih|Whh]
                             float* __restrict__ bias)           // 3072
{
    int r = blockIdx.y;
    int k = blockIdx.x * 256 + threadIdx.x;
    float a = Wih[r * H + k];
    float b = Whh[r * H + k];
    Wc[r * H + k] = __float2bfloat16(a + b);
    Wcat[r * 1536 + k] = __float2bfloat16(a);
    Wcat[r * 1536 + H + k] = __float2bfloat16(b);
    if (blockIdx.x == 0 && threadIdx.x == 0) bias[r] = bih[r] + bhh[r];
}

__global__ void prep_post(const float* __restrict__ Wpost, __hip_bfloat16* __restrict__ Wp)
{
    int r = blockIdx.y;
    int k = blockIdx.x * 256 + threadIdx.x;
    Wp[r * H + k] = (r < 72) ? __float2bfloat16(Wpost[r * H + k]) : __float2bfloat16(0.0f);
}

__global__ void prep_state(const float* __restrict__ src, const float* __restrict__ h0,
                           const float* __restrict__ c0,
                           __hip_bfloat16* __restrict__ A0,  // 256 x 1536 [x0|h0]
                           float* __restrict__ c_ws)         // 256 x 768
{
    int b = blockIdx.y;
    int k = blockIdx.x * 256 + threadIdx.x;
    A0[b * 1536 + k] = __float2bfloat16(src[(b * 16 + 15) * H + k]);   // src[:, -1, :]
    A0[b * 1536 + H + k] = __float2bfloat16(h0[b * H + k]);
    c_ws[b * H + k] = c0[b * H + k];
}

#define CNT_STRIDE 64   // one counter per 256 B line: no cross-group false sharing

__global__ void init_barrier(unsigned* __restrict__ cnt)
{
    cnt[threadIdx.x] = 0u;   // 1024 threads cover 16 * CNT_STRIDE
}

// ---------------- step 0 only: fused gates GEMM + cell (K = 1536) ----------------
__global__ __launch_bounds__(64) void lstm_step(
    const __hip_bfloat16* __restrict__ A,   // B x K  ([x0|h0])
    const __hip_bfloat16* __restrict__ W,   // 3072 x K (Wcat)
    const float* __restrict__ bias,
    float* __restrict__ c,                  // B x H fp32 (in place)
    __hip_bfloat16* __restrict__ h_out,     // B x H bf16 (= outs[0])
    int K)
{
    const int jt = blockIdx.x;
    const int mt = blockIdx.y;
    const int lane = threadIdx.x;
    const int col = lane & 15;
    const int quad = lane >> 4;

    const short* Ap  = (const short*)A + (size_t)(mt * 16 + col) * K + quad * 8;
    const short* Wb  = (const short*)W;
    const short* Wp0 = Wb + (size_t)(0 * H + jt * 16 + col) * K + quad * 8;
    const short* Wp1 = Wb + (size_t)(1 * H + jt * 16 + col) * K + quad * 8;
    const short* Wp2 = Wb + (size_t)(2 * H + jt * 16 + col) * K + quad * 8;
    const short* Wp3 = Wb + (size_t)(3 * H + jt * 16 + col) * K + quad * 8;

    f32x4 acc0 = {0.f,0.f,0.f,0.f}, acc1 = {0.f,0.f,0.f,0.f};
    f32x4 acc2 = {0.f,0.f,0.f,0.f}, acc3 = {0.f,0.f,0.f,0.f};

    for (int k = 0; k < K; k += 32) {
        short8 a  = *(const short8*)(Ap + k);
        short8 b0 = *(const short8*)(Wp0 + k);
        short8 b1 = *(const short8*)(Wp1 + k);
        short8 b2 = *(const short8*)(Wp2 + k);
        short8 b3 = *(const short8*)(Wp3 + k);
        acc0 = __builtin_amdgcn_mfma_f32_16x16x32_bf16(a, b0, acc0, 0, 0, 0);
        acc1 = __builtin_amdgcn_mfma_f32_16x16x32_bf16(a, b1, acc1, 0, 0, 0);
        acc2 = __builtin_amdgcn_mfma_f32_16x16x32_bf16(a, b2, acc2, 0, 0, 0);
        acc3 = __builtin_amdgcn_mfma_f32_16x16x32_bf16(a, b3, acc3, 0, 0, 0);
    }

    const int j = jt * 16 + col;
    const float bi = bias[0 * H + j];
    const float bf = bias[1 * H + j];
    const float bg = bias[2 * H + j];
    const float bo = bias[3 * H + j];

#pragma unroll
    for (int r = 0; r < 4; ++r) {
        const int bidx = mt * 16 + quad * 4 + r;
        float ig = acc0[r] + bi;
        float fg = acc1[r] + bf;
        float gg = acc2[r] + bg;
        float og = acc3[r] + bo;
        float cold = c[bidx * H + j];
        float cn = sigm(fg) * cold + sigm(ig) * tanh_fast(gg);
        float hn = sigm(og) * tanh_fast(cn);
        c[bidx * H + j] = cn;
        h_out[bidx * H + j] = __float2bfloat16(hn);
    }
}

// ---------------- persistent recurrence: steps 1..99 ----------------
// grid 256 blocks (16 mtg x 16 jg) x 768 threads (12 waves = 3 jt x 4 gates).
// Weight slice pinned in VGPRs via inline-asm loads (compiler cannot remat/sink).
// h via AGENT-scope relaxed atomics (LLC-coherent), per-group padded counters.
#define LDS_H_STRIDE 776   // 768 + 8 shorts pad
#define XCH_STRIDE   17    // 16 + 1 pad floats

#define LDW(nm, idx) \
    asm volatile("global_load_dwordx4 %0, %1, off" \
                 : "=v"(nm) : "v"(wptr + (idx) * 32))

#define KSTEP(nm, idx) { \
    short8 a_ = *(const short8*)(&lds_h[col * LDS_H_STRIDE + (idx) * 32 + quad * 8]); \
    acc = __builtin_amdgcn_mfma_f32_16x16x32_bf16(a_, nm, acc, 0, 0, 0); }

__global__ __launch_bounds__(768, 3) void lstm_persist(
    const __hip_bfloat16* __restrict__ Wc,   // 3072 x 768 bf16
    const float* __restrict__ bias,          // 3072
    const float* __restrict__ c_ws,          // B x H fp32 (after step 0)
    __hip_bfloat16* outs,                    // T x B x H bf16 (outs[0] ready)
    unsigned* cnt)                           // 16 padded group counters (zeroed)
{
    const int mtg  = blockIdx.x >> 4;    // batch group 0..15 (16 batches)
    const int jg   = blockIdx.x & 15;    // j group 0..15 (48 j values)
    const int tid  = threadIdx.x;
    const int wave = tid >> 6;           // 0..11
    const int lane = tid & 63;
    const int col  = lane & 15;
    const int quad = lane >> 4;
    const int jt_l = wave >> 2;          // 0..2  local j-tile
    const int gate = wave & 3;           // 0..3  (i,f,g,o)
    const int j    = jg * 48 + jt_l * 16 + col;   // this wave's j column

    __shared__ short lds_h[16 * LDS_H_STRIDE];        // 24832 B staged h tile
    __shared__ float xch[12 * 16 * XCH_STRIDE];       // 13056 B gate exchange

    // ---- pin resident weight slice in VGPRs: 24 x short8 = 96 VGPRs ----
    const short* wptr = (const short*)Wc + (size_t)(gate * H + j) * H + quad * 8;
    short8 w00,w01,w02,w03,w04,w05,w06,w07,w08,w09,w10,w11,
           w12,w13,w14,w15,w16,w17,w18,w19,w20,w21,w22,w23;
    LDW(w00,0);  LDW(w01,1);  LDW(w02,2);  LDW(w03,3);
    LDW(w04,4);  LDW(w05,5);  LDW(w06,6);  LDW(w07,7);
    LDW(w08,8);  LDW(w09,9);  LDW(w10,10); LDW(w11,11);
    LDW(w12,12); LDW(w13,13); LDW(w14,14); LDW(w15,15);
    LDW(w16,16); LDW(w17,17); LDW(w18,18); LDW(w19,19);
    LDW(w20,20); LDW(w21,21); LDW(w22,22); LDW(w23,23);
    asm volatile("s_waitcnt vmcnt(0)" ::: "memory");

    // ---- cell-role state (threads 0..383: two adjacent-j cells each) ----
    const int p    = tid;                 // pair id if < 384
    const int bb   = p / 24;              // local batch 0..15
    const int jp   = p % 24;
    const int jloc = jp * 2;              // local j 0..46 (even)
    const int cjt  = jloc >> 4;           // j-tile of the pair
    const int jcol = jloc & 15;
    const int bglob = mtg * 16 + bb;
    const int jglob = jg * 48 + jloc;
    float c0v = 0.f, c1v = 0.f;
    float bi0=0,bi1=0,bf0=0,bf1=0,bg0=0,bg1=0,bo0=0,bo1=0;
    if (p < 384) {
        c0v = c_ws[(size_t)bglob * H + jglob];
        c1v = c_ws[(size_t)bglob * H + jglob + 1];
        bi0 = bias[0*H + jglob]; bi1 = bias[0*H + jglob + 1];
        bf0 = bias[1*H + jglob]; bf1 = bias[1*H + jglob + 1];
        bg0 = bias[2*H + jglob]; bg1 = bias[2*H + jglob + 1];
        bo0 = bias[3*H + jglob]; bo1 = bias[3*H + jglob + 1];
    }

    const short* outs_s = (const short*)outs;
    unsigned* my_cnt = &cnt[mtg * CNT_STRIDE];

    for (int t = 1; t < T; ++t) {
        // ---- wait: all 16 blocks of this batch group finished step t-1 ----
        const unsigned target = 16u * (unsigned)(t - 1);
        if (tid == 0 && target) {
            int guard = 0;
            while (__hip_atomic_load(my_cnt, __ATOMIC_RELAXED,
                                     __HIP_MEMORY_SCOPE_AGENT) < target) {
                __builtin_amdgcn_s_sleep(1);
                if (++guard > (1 << 24)) break;   // safety valve vs hang
            }
        }
        __syncthreads();   // (A) broadcast "go"; also WAR for lds_h vs prev reads

        // ---- stage h(t-1)[16 batches][768] -> LDS via LLC-coherent 8B loads ----
        const u64* hsrc8 = (const u64*)(outs_s + (size_t)(t - 1) * B * H
                                               + (size_t)mtg * 16 * H);
#pragma unroll
        for (int i = 0; i < 4; ++i) {
            int idx = tid + i * 768;          // 0..3071 (16 rows x 192 ulongs)
            int br  = idx / 192;
            int ch  = idx % 192;
            u64 v = __hip_atomic_load(&hsrc8[br * 192 + ch],
                                      __ATOMIC_RELAXED, __HIP_MEMORY_SCOPE_AGENT);
            *(u64*)&lds_h[br * LDS_H_STRIDE + ch * 4] = v;
        }
        __syncthreads();   // (B) lds_h ready; also WAR for xch vs prev cell reads

        // ---- this wave: 16 batches x 16 j, ONE gate, K=768 ----
        f32x4 acc = {0.f, 0.f, 0.f, 0.f};
        KSTEP(w00,0)  KSTEP(w01,1)  KSTEP(w02,2)  KSTEP(w03,3)
        KSTEP(w04,4)  KSTEP(w05,5)  KSTEP(w06,6)  KSTEP(w07,7)
        KSTEP(w08,8)  KSTEP(w09,9)  KSTEP(w10,10) KSTEP(w11,11)
        KSTEP(w12,12) KSTEP(w13,13) KSTEP(w14,14) KSTEP(w15,15)
        KSTEP(w16,16) KSTEP(w17,17) KSTEP(w18,18) KSTEP(w19,19)
        KSTEP(w20,20) KSTEP(w21,21) KSTEP(w22,22) KSTEP(w23,23)

        // ---- exchange gate tiles through LDS ----
        float* xw = &xch[(size_t)wave * 16 * XCH_STRIDE];
#pragma unroll
        for (int r = 0; r < 4; ++r)
            xw[(quad * 4 + r) * XCH_STRIDE + col] = acc[r];
        __syncthreads();   // (C) xch ready

        // ---- cell update: threads 0..383, two adjacent j each ----
        if (p < 384) {
            const float* xg = &xch[(size_t)(cjt * 4) * 16 * XCH_STRIDE + bb * XCH_STRIDE + jcol];
            const int gs = 16 * XCH_STRIDE;
            float i0 = xg[0*gs] + bi0, i1 = xg[0*gs + 1] + bi1;
            float f0 = xg[1*gs] + bf0, f1 = xg[1*gs + 1] + bf1;
            float g0 = xg[2*gs] + bg0, g1 = xg[2*gs + 1] + bg1;
            float o0 = xg[3*gs] + bo0, o1 = xg[3*gs + 1] + bo1;
            float cn0 = sigm(f0) * c0v + sigm(i0) * tanh_fast(g0);
            float cn1 = sigm(f1) * c1v + sigm(i1) * tanh_fast(g1);
            c0v = cn0; c1v = cn1;
            __hip_bfloat16 h0b = __float2bfloat16(sigm(o0) * tanh_fast(cn0));
            __hip_bfloat16 h1b = __float2bfloat16(sigm(o1) * tanh_fast(cn1));
            unsigned u = (unsigned)(*(unsigned short*)&h0b)
                       | ((unsigned)(*(unsigned short*)&h1b) << 16);
            unsigned* dst = (unsigned*)(outs_s + (size_t)t * B * H
                                               + (size_t)bglob * H + jglob);
            __hip_atomic_store(dst, u, __ATOMIC_RELAXED, __HIP_MEMORY_SCOPE_AGENT);
        }

        // ---- publish step t ----
        asm volatile("s_waitcnt vmcnt(0)" ::: "memory");  // own h stores at LLC
        __syncthreads();   // (D) all threads drained before signal
        if (tid == 0) atomicAdd(my_cnt, 1u);
    }
}

// ---------------- post projection ----------------
__global__ __launch_bounds__(64) void proj(
    const __hip_bfloat16* __restrict__ Hs,   // T x B x H
    const __hip_bfloat16* __restrict__ Wp,   // 80 x H (padded bf16)
    const float* __restrict__ bpost,         // 72
    float* __restrict__ out)                 // B x T x 72
{
    const int mt = blockIdx.x;
    const int lane = threadIdx.x;
    const int col = lane & 15;
    const int quad = lane >> 4;

    const short* Ap = (const short*)Hs + (size_t)(mt * 16 + col) * H + quad * 8;
    const short* Wb = (const short*)Wp;

    f32x4 acc[5];
#pragma unroll
    for (int nt = 0; nt < 5; ++nt) acc[nt] = (f32x4){0.f, 0.f, 0.f, 0.f};

    for (int k = 0; k < H; k += 32) {
        short8 a = *(const short8*)(Ap + k);
#pragma unroll
        for (int nt = 0; nt < 5; ++nt) {
            short8 b = *(const short8*)(Wb + (size_t)(nt * 16 + col) * H + quad * 8 + k);
            acc[nt] = __builtin_amdgcn_mfma_f32_16x16x32_bf16(a, b, acc[nt], 0, 0, 0);
        }
    }

#pragma unroll
    for (int nt = 0; nt < 5; ++nt) {
        const int o = nt * 16 + col;
        if (o < 72) {
            const float bb = bpost[o];
#pragma unroll
            for (int r = 0; r < 4; ++r) {
                const int m = mt * 16 + quad * 4 + r;
                const int t = m >> 8;
                const int b = m & 255;
                out[((size_t)b * T + t) * 72 + o] = acc[nt][r] + bb;
            }
        }
    }
}

// ---------------- launch ----------------

extern "C" void kernel_launch(void* const* d_in, const int* in_sizes, int n_in,
                              void* d_out, int out_size, void* d_ws, size_t ws_size,
                              hipStream_t stream) {
    const float* src   = (const float*)d_in[0];
    const float* h0    = (const float*)d_in[2];
    const float* c0    = (const float*)d_in[3];
    const float* Wih   = (const float*)d_in[4];
    const float* Whh   = (const float*)d_in[5];
    const float* bih   = (const float*)d_in[6];
    const float* bhh   = (const float*)d_in[7];
    const float* Wpost = (const float*)d_in[8];
    const float* bpost = (const float*)d_in[9];
    float* out = (float*)d_out;

    char* ws = (char*)d_ws;
    __hip_bfloat16* Wcat = (__hip_bfloat16*)(ws + 0);          //  9,437,184 B
    __hip_bfloat16* Wc   = (__hip_bfloat16*)(ws + 9437184);    //  4,718,592 B
    float*          bias = (float*)(ws + 14155776);            //     12,288 B
    __hip_bfloat16* Wp   = (__hip_bfloat16*)(ws + 14168064);   //    122,880 B
    __hip_bfloat16* A0   = (__hip_bfloat16*)(ws + 14290944);   //    786,432 B
    float*          c_ws = (float*)(ws + 15077376);            //    786,432 B
    __hip_bfloat16* outs = (__hip_bfloat16*)(ws + 15863808);   // 39,321,600 B
    unsigned*       cnt  = (unsigned*)(ws + 55185408);         //      4,096 B

    prep_weights<<<dim3(3, G4), 256, 0, stream>>>(Wih, Whh, bih, bhh, Wc, Wcat, bias);
    prep_post<<<dim3(3, 80), 256, 0, stream>>>(Wpost, Wp);
    prep_state<<<dim3(3, B), 256, 0, stream>>>(src, h0, c0, A0, c_ws);
    init_barrier<<<1, 1024, 0, stream>>>(cnt);

    // step 0: gates = [x0|h0] @ [Wih|Whh]^T + bias   (K = 1536)
    lstm_step<<<dim3(48, 16), 64, 0, stream>>>(A0, Wcat, bias, c_ws, outs, 1536);

    // steps 1..99 in one persistent kernel
    lstm_persist<<<256, 768, 0, stream>>>(Wc, bias, c_ws, outs, cnt);

    proj<<<1600, 64, 0, stream>>>(outs, Wp, bpost, out);
}